// Round 14
// baseline (2466.006 us; speedup 1.0000x reference)
//
#include <hip/hip_runtime.h>

#define SEQ 512
#define BATCH 64
#define NN 1024
#define SS 64
#define CH 16                 // steps per readiness chunk
#define GB 960                // gather blocks; lif blocks are GB..GB+63

typedef float v4f __attribute__((ext_vector_type(4)));
typedef unsigned long long u64;

// lgkm-only barrier (no vmcnt drain): LDS settled, global loads/stores in flight.
#define RAW_BARRIER() asm volatile("s_waitcnt lgkmcnt(0)\n\ts_barrier" ::: "memory")

// ---- transpose W1 (1024x1024 f32): W1T[i*N+j] = W1[j*N+i] ----
__global__ void transpose1(const float* __restrict__ A, float* __restrict__ At) {
    __shared__ float tile[32][33];
    int bx = blockIdx.x * 32, by = blockIdx.y * 32;
    int tx = threadIdx.x, ty = threadIdx.y;   // block 32x8
#pragma unroll
    for (int r = 0; r < 32; r += 8)
        tile[ty + r][tx] = A[(by + ty + r) * NN + (bx + tx)];
    __syncthreads();
#pragma unroll
    for (int r = 0; r < 32; r += 8)
        At[(bx + ty + r) * NN + (by + tx)] = tile[tx][ty + r];
}

// ---- fused producer/consumer kernel ----
// blocks [0,GB): gather role — I1[tt,b,n] = sum_{s<num} W1T[ids[s],n], t-major
//   grid-stride, NT stores + vmcnt drain + block barrier + RELEASE tick.
// blocks [GB,GB+64): lif role — R13 recurrence; per-chunk spin + ACQUIRE fence.
__global__ __launch_bounds__(256, 4) void fused_kernel(
    const float* __restrict__ W1T, const float* __restrict__ W2,
    const float* __restrict__ decay1, const float* __restrict__ decay2,
    const float* __restrict__ th1, const float* __restrict__ th2,
    const float* __restrict__ init1, const float* __restrict__ init2,
    const int* __restrict__ inp_ids, const int* __restrict__ inp_num,
    float* __restrict__ I1buf, unsigned* __restrict__ done,
    float* __restrict__ state, float* __restrict__ out,
    int t0, int nst)
{
    const int bid = blockIdx.x;

    if (bid < GB) {
        // ================= gather role =================
        const int j4 = threadIdx.x << 2;
        const int ntiles = nst * BATCH;
        for (int tile = bid; tile < ntiles; tile += GB) {
            const int tt = tile >> 6;              // t-major: early chunks first
            const int b  = tile & 63;
            const int t  = t0 + tt;
            const int num = inp_num[t * BATCH + b];
            const int* ids = inp_ids + ((size_t)t * BATCH + b) * SS; // s_load path

            v4f a0 = {0,0,0,0}, a1 = a0, a2 = a0, a3 = a0;
            const int nch = num >> 2;
            const int rem = num & 3;
#pragma unroll
            for (int c = 0; c < 16; ++c) {
                if (c < nch) {                     // block-uniform
                    const int r = c << 2;
                    const v4f w0 = *(const v4f*)(W1T + ((size_t)ids[r+0] << 10) + j4);
                    const v4f w1 = *(const v4f*)(W1T + ((size_t)ids[r+1] << 10) + j4);
                    const v4f w2 = *(const v4f*)(W1T + ((size_t)ids[r+2] << 10) + j4);
                    const v4f w3 = *(const v4f*)(W1T + ((size_t)ids[r+3] << 10) + j4);
#pragma unroll
                    for (int k = 0; k < 4; ++k) {
                        a0[k] = __fadd_rn(a0[k], w0[k]);
                        a1[k] = __fadd_rn(a1[k], w1[k]);
                        a2[k] = __fadd_rn(a2[k], w2[k]);
                        a3[k] = __fadd_rn(a3[k], w3[k]);
                    }
                }
            }
            if (rem > 0) {
                const int r4 = nch << 2;
                const v4f w0 = *(const v4f*)(W1T + ((size_t)ids[r4+0] << 10) + j4);
#pragma unroll
                for (int k = 0; k < 4; ++k) a0[k] = __fadd_rn(a0[k], w0[k]);
                if (rem > 1) {
                    const v4f w1 = *(const v4f*)(W1T + ((size_t)ids[r4+1] << 10) + j4);
#pragma unroll
                    for (int k = 0; k < 4; ++k) a1[k] = __fadd_rn(a1[k], w1[k]);
                }
                if (rem > 2) {
                    const v4f w2 = *(const v4f*)(W1T + ((size_t)ids[r4+2] << 10) + j4);
#pragma unroll
                    for (int k = 0; k < 4; ++k) a2[k] = __fadd_rn(a2[k], w2[k]);
                }
            }
            v4f o;
#pragma unroll
            for (int k = 0; k < 4; ++k)
                o[k] = __fadd_rn(__fadd_rn(a0[k], a1[k]), __fadd_rn(a2[k], a3[k]));
            // NT store: bypasses writer L2 -> memory-side (cross-XCD safe)
            __builtin_nontemporal_store(o,
                (v4f*)(I1buf + ((size_t)tt * BATCH + b) * NN + j4));

            asm volatile("s_waitcnt vmcnt(0)" ::: "memory"); // my slice landed
            __syncthreads();                                 // whole tile landed
            if (threadIdx.x == 0)
                __hip_atomic_fetch_add(&done[tt >> 4], 1u,
                                       __ATOMIC_RELEASE, __HIP_MEMORY_SCOPE_AGENT);
        }
        return;
    }

    // ================= lif role (R13 body + chunk waits) =================
    const int b    = bid - GB;
    const int i    = threadIdx.x;      // 0..255
    const int lane = i & 63;
    const int w    = i >> 6;           // wave 0..3
    const int n0   = i << 2;           // neurons n0..n0+3
    const int nchk = (nst + CH - 1) / CH;

    __shared__ u64 lds_w[2][4];
    __shared__ u64 lds_wc[2][4];
    __shared__ int lds_slots[NN];

    float v1[4], v2[4], d1v[4], d2v[4], o1v[4], o2v[4];
    float t1v[4], t2v[4], t1bv[4], t2bv[4];
    const float* v1src = t0 ? (state + 0 * BATCH * NN) : init1;
    const float* v2src = t0 ? (state + 1 * BATCH * NN) : init2;
#pragma unroll
    for (int k = 0; k < 4; ++k) {
        const int n = n0 + k;
        v1[k] = v1src[b * NN + n];  v2[k] = v2src[b * NN + n];
        d1v[k] = decay1[n];  d2v[k] = decay2[n];
        t1v[k] = th1[n];     t2v[k] = th2[n];
        t1bv[k] = __fmul_rn(0.9f, t1v[k]);
        t2bv[k] = __fmul_rn(0.9f, t2v[k]);
        o1v[k] = __fadd_rn(1.0f, -d1v[k]);
        o2v[k] = __fadd_rn(1.0f, -d2v[k]);
    }

    float* out_ids1 = out;
    float* out_ids2 = out + (size_t)SEQ * BATCH * SS;
    float* out_cnt1 = out + (size_t)2 * SEQ * BATCH * SS;
    float* out_cnt2 = out_cnt1 + (size_t)SEQ * BATCH * 2;
    float* out_st1  = out_cnt2 + (size_t)SEQ * BATCH * 2;
    float* out_st2  = out_st1  + (size_t)SEQ * BATCH * NN;

    const u64 lmask_lt = (1ull << lane) - 1ull;

    u64 B1p[4], B2p[4];
    float v2pp[4];

    auto WAITCH = [&](int c) {
        const int base  = c * CH;
        const int steps = (nst - base) < CH ? (nst - base) : CH;
        const unsigned needv = (unsigned)(steps * BATCH);
        while (__hip_atomic_load(&done[c], __ATOMIC_RELAXED,
                                 __HIP_MEMORY_SCOPE_AGENT) < needv)
            __builtin_amdgcn_s_sleep(2);
    };

    auto CONSUME = [&](int s, int ppar) {
        const u64* wp = lds_w[ppar];
        const u64 x0 = wp[0], x1 = wp[1], x2 = wp[2], x3 = wp[3];
        const u64 tot = x0 + x1 + x2 + x3;
        const u64 off = (w > 0 ? x0 : 0) + (w > 1 ? x1 : 0) + (w > 2 ? x2 : 0);
        const int totalA  = (int)(tot & 0xFFFF);
        const int total2A = (int)((tot >> 16) & 0xFFFF);
        const int woff1   = (int)(off & 0xFFFF);

        const int T1 = (int)(__popcll(B1p[0] & lmask_lt) + __popcll(B1p[1] & lmask_lt)
                           + __popcll(B1p[2] & lmask_lt) + __popcll(B1p[3] & lmask_lt));
        const size_t row = (size_t)s * BATCH + b;

        int run = 0;
        int lt1s[4]; bool bk1[4];
#pragma unroll
        for (int k = 0; k < 4; ++k) {
            bk1[k] = (B1p[k] >> lane) & 1ull;
            lt1s[k] = woff1 + T1 + run;
            run += bk1[k];
            const int slot = bk1[k] ? lt1s[k] : (totalA + (n0 + k) - lt1s[k]);
            if (slot < SS)
                __builtin_nontemporal_store((float)(n0 + k),
                                            &out_ids1[row * SS + slot]);
        }
        {
            const v4f sv = {v1[0], v1[1], v1[2], v1[3]};
            __builtin_nontemporal_store(sv, (v4f*)(out_st1 + row * NN + n0));
        }
        if (i == 0) {
            __builtin_nontemporal_store((float)totalA,  &out_cnt1[row * 2 + 0]);
            __builtin_nontemporal_store((float)total2A, &out_cnt1[row * 2 + 1]);
        }

        int totalB, total2B, woff2;
        u64 B2u[4]; float v2u[4];
        if (totalA > 0) {
            run = 0;
#pragma unroll
            for (int k = 0; k < 4; ++k)
                if (bk1[k]) lds_slots[lt1s[k]] = n0 + k;
            RAW_BARRIER();
            float I2[4] = {0.0f, 0.0f, 0.0f, 0.0f};
            for (int kk = 0; kk < totalA; ++kk) {
                const int sid = lds_slots[kk];
#pragma unroll
                for (int k = 0; k < 4; ++k)
                    I2[k] = __fadd_rn(I2[k], W2[(size_t)(n0 + k) * NN + sid]);
            }
            u64 Bn2c[4];
#pragma unroll
            for (int k = 0; k < 4; ++k) {
                v2u[k] = __fadd_rn(v2pp[k], __fmul_rn(o2v[k], I2[k]));
                B2u[k] = __ballot(v2u[k] > t2v[k]);
                Bn2c[k] = __ballot(v2u[k] > t2bv[k]);
            }
            const u64 c2c  = __popcll(B2u[0]) + __popcll(B2u[1])
                           + __popcll(B2u[2]) + __popcll(B2u[3]);
            const u64 cn2c = __popcll(Bn2c[0]) + __popcll(Bn2c[1])
                           + __popcll(Bn2c[2]) + __popcll(Bn2c[3]);
            if (lane == 0) lds_wc[ppar][w] = c2c | (cn2c << 16);
            RAW_BARRIER();
            const u64* cp = lds_wc[ppar];
            const u64 y0 = cp[0], y1 = cp[1], y2 = cp[2], y3 = cp[3];
            const u64 ct = y0 + y1 + y2 + y3;
            const u64 co = (w > 0 ? y0 : 0) + (w > 1 ? y1 : 0) + (w > 2 ? y2 : 0);
            totalB  = (int)(ct & 0xFFFF);
            total2B = (int)((ct >> 16) & 0xFFFF);
            woff2   = (int)(co & 0xFFFF);
        } else {
#pragma unroll
            for (int k = 0; k < 4; ++k) { B2u[k] = B2p[k]; v2u[k] = v2pp[k]; }
            totalB  = (int)((tot >> 32) & 0xFFFF);
            total2B = (int)(tot >> 48);
            woff2   = (int)((off >> 32) & 0xFFFF);
        }

        const int T2 = (int)(__popcll(B2u[0] & lmask_lt) + __popcll(B2u[1] & lmask_lt)
                           + __popcll(B2u[2] & lmask_lt) + __popcll(B2u[3] & lmask_lt));
        run = 0;
        v4f sv2;
#pragma unroll
        for (int k = 0; k < 4; ++k) {
            const bool bk = (B2u[k] >> lane) & 1ull;
            const int lt = woff2 + T2 + run;
            run += bk;
            const int slot = bk ? lt : (totalB + (n0 + k) - lt);
            if (slot < SS)
                __builtin_nontemporal_store((float)(n0 + k),
                                            &out_ids2[row * SS + slot]);
            sv2[k] = bk ? 0.0f : v2u[k];
            v2[k] = sv2[k];
        }
        __builtin_nontemporal_store(sv2, (v4f*)(out_st2 + row * NN + n0));
        if (i == 0) {
            __builtin_nontemporal_store((float)totalB,  &out_cnt2[row * 2 + 0]);
            __builtin_nontemporal_store((float)total2B, &out_cnt2[row * 2 + 1]);
        }
    };

    // prologue waits: chunks 0 and 1 ready, then fence, then prefetch
    WAITCH(0);
    if (nchk > 1) WAITCH(1);
    __builtin_amdgcn_fence(__ATOMIC_ACQUIRE, "agent");

    v4f f0 = *(const v4f*)(I1buf + ((size_t)0 * BATCH + b) * NN + n0);
    v4f f1 = (nst > 1)
        ? *(const v4f*)(I1buf + ((size_t)1 * BATCH + b) * NN + n0) : f0;

    for (int tt = 0; tt < nst; ++tt) {
        const int par = tt & 1;
        if (tt > 0 && (tt & (CH - 1)) == 0) {
            const int c = tt >> 4;
            if (c + 1 < nchk) WAITCH(c + 1);
            __builtin_amdgcn_fence(__ATOMIC_ACQUIRE, "agent");
        }
        v4f f2 = f0;
        if (tt + 2 < nst)
            f2 = *(const v4f*)(I1buf + ((size_t)(tt + 2) * BATCH + b) * NN + n0);

        if (tt > 0) CONSUME(t0 + tt - 1, par ^ 1);

        const v4f f = f0; f0 = f1; f1 = f2;
        u64 Bn1[4], Bn2[4];
#pragma unroll
        for (int k = 0; k < 4; ++k) {
            v1[k] = __fadd_rn(__fmul_rn(d1v[k], v1[k]), __fmul_rn(o1v[k], f[k]));
            B1p[k] = __ballot(v1[k] > t1v[k]);
            Bn1[k] = __ballot(v1[k] > t1bv[k]);
            if ((B1p[k] >> lane) & 1ull) v1[k] = 0.0f;
            v2pp[k] = __fmul_rn(d2v[k], v2[k]);
            B2p[k] = __ballot(v2pp[k] > t2v[k]);
            Bn2[k] = __ballot(v2pp[k] > t2bv[k]);
        }
        const u64 c1  = __popcll(B1p[0]) + __popcll(B1p[1])
                      + __popcll(B1p[2]) + __popcll(B1p[3]);
        const u64 cn1 = __popcll(Bn1[0]) + __popcll(Bn1[1])
                      + __popcll(Bn1[2]) + __popcll(Bn1[3]);
        const u64 c2  = __popcll(B2p[0]) + __popcll(B2p[1])
                      + __popcll(B2p[2]) + __popcll(B2p[3]);
        const u64 cn2 = __popcll(Bn2[0]) + __popcll(Bn2[1])
                      + __popcll(Bn2[2]) + __popcll(Bn2[3]);
        if (lane == 0)
            lds_w[par][w] = c1 | (cn1 << 16) | (c2 << 32) | (cn2 << 48);

        RAW_BARRIER();
    }

    CONSUME(t0 + nst - 1, (nst - 1) & 1);

#pragma unroll
    for (int k = 0; k < 4; ++k) {
        state[0 * BATCH * NN + b * NN + n0 + k] = v1[k];
        state[1 * BATCH * NN + b * NN + n0 + k] = v2[k];
    }
}

extern "C" void kernel_launch(void* const* d_in, const int* in_sizes, int n_in,
                              void* d_out, int out_size, void* d_ws, size_t ws_size,
                              hipStream_t stream) {
    const float* W1     = (const float*)d_in[0];
    const float* W2     = (const float*)d_in[1];
    const float* decay1 = (const float*)d_in[2];
    const float* decay2 = (const float*)d_in[3];
    const float* th1    = (const float*)d_in[4];
    const float* th2    = (const float*)d_in[5];
    const float* init1  = (const float*)d_in[6];
    const float* init2  = (const float*)d_in[7];
    const int* inp_ids  = (const int*)d_in[8];
    const int* inp_num  = (const int*)d_in[9];
    float* out = (float*)d_out;

    float* W1T      = (float*)d_ws;                                // 4 MB
    float* state    = (float*)((char*)d_ws + (size_t)NN * NN * 4); // 512 KB
    unsigned* done  = (unsigned*)(state + (size_t)2 * BATCH * NN); // 128 B (pad 256)
    float* I1buf    = (float*)((char*)done + 256);
    const size_t used  = (size_t)NN * NN * 4 + (size_t)2 * BATCH * NN * 4 + 256;
    const size_t avail = ws_size > used ? ws_size - used : 0;
    int tc = (int)(avail / ((size_t)BATCH * NN * 4));              // steps per launch
    if (tc > SEQ) tc = SEQ;
    if (tc < 1) tc = 1;

    dim3 tb(32, 8, 1), tg(NN / 32, NN / 32, 1);
    transpose1<<<tg, tb, 0, stream>>>(W1, W1T);
    for (int t0 = 0; t0 < SEQ; t0 += tc) {
        const int nst = (SEQ - t0 < tc) ? (SEQ - t0) : tc;
        hipMemsetAsync(done, 0, ((SEQ + CH - 1) / CH) * sizeof(unsigned), stream);
        fused_kernel<<<GB + BATCH, 256, 0, stream>>>(W1T, W2, decay1, decay2,
                                                     th1, th2, init1, init2,
                                                     inp_ids, inp_num,
                                                     I1buf, done, state, out,
                                                     t0, nst);
    }
}

// Round 15
// 618.953 us; speedup vs baseline: 3.9842x; 3.9842x over previous
//
#include <hip/hip_runtime.h>

#define SEQ 512
#define BATCH 64
#define NN 1024
#define SS 64

typedef float v4f __attribute__((ext_vector_type(4)));
typedef unsigned long long u64;

// lgkm-only barrier (no vmcnt drain) — fallback kernel only
#define RAW_BARRIER() asm volatile("s_waitcnt lgkmcnt(0)\n\ts_barrier" ::: "memory")

// ---- transpose W1 (1024x1024 f32): W1T[i*N+j] = W1[j*N+i] ----
__global__ void transpose1(const float* __restrict__ A, float* __restrict__ At) {
    __shared__ float tile[32][33];
    int bx = blockIdx.x * 32, by = blockIdx.y * 32;
    int tx = threadIdx.x, ty = threadIdx.y;   // block 32x8
#pragma unroll
    for (int r = 0; r < 32; r += 8)
        tile[ty + r][tx] = A[(by + ty + r) * NN + (bx + tx)];
    __syncthreads();
#pragma unroll
    for (int r = 0; r < 32; r += 8)
        At[(bx + ty + r) * NN + (by + tx)] = tile[tx][ty + r];
}

// ---- phase 1: I1[tt,b,n] = sum_{s<num} W1T[ids[s], n] (unchanged from R13) ----
__global__ __launch_bounds__(256) void gather_kernel(
    const float* __restrict__ W1T,
    const int* __restrict__ inp_ids, const int* __restrict__ inp_num,
    float* __restrict__ I1buf, int t0)
{
    const int bid = blockIdx.x;
    const int tt  = bid >> 6;
    const int b   = bid & 63;
    const int t   = t0 + tt;
    const int j4  = threadIdx.x << 2;
    const int num = inp_num[t * BATCH + b];
    const int* ids = inp_ids + ((size_t)t * BATCH + b) * SS;  // uniform -> s_load

    v4f a0 = {0,0,0,0}, a1 = a0, a2 = a0, a3 = a0;
    const int nch = num >> 2;
    const int rem = num & 3;
#pragma unroll
    for (int c = 0; c < 16; ++c) {
        if (c < nch) {                             // block-uniform
            const int r = c << 2;
            const v4f w0 = *(const v4f*)(W1T + ((size_t)ids[r+0] << 10) + j4);
            const v4f w1 = *(const v4f*)(W1T + ((size_t)ids[r+1] << 10) + j4);
            const v4f w2 = *(const v4f*)(W1T + ((size_t)ids[r+2] << 10) + j4);
            const v4f w3 = *(const v4f*)(W1T + ((size_t)ids[r+3] << 10) + j4);
#pragma unroll
            for (int k = 0; k < 4; ++k) {
                a0[k] = __fadd_rn(a0[k], w0[k]);
                a1[k] = __fadd_rn(a1[k], w1[k]);
                a2[k] = __fadd_rn(a2[k], w2[k]);
                a3[k] = __fadd_rn(a3[k], w3[k]);
            }
        }
    }
    if (rem > 0) {
        const int r4 = nch << 2;
        const v4f w0 = *(const v4f*)(W1T + ((size_t)ids[r4+0] << 10) + j4);
#pragma unroll
        for (int k = 0; k < 4; ++k) a0[k] = __fadd_rn(a0[k], w0[k]);
        if (rem > 1) {
            const v4f w1 = *(const v4f*)(W1T + ((size_t)ids[r4+1] << 10) + j4);
#pragma unroll
            for (int k = 0; k < 4; ++k) a1[k] = __fadd_rn(a1[k], w1[k]);
        }
        if (rem > 2) {
            const v4f w2 = *(const v4f*)(W1T + ((size_t)ids[r4+2] << 10) + j4);
#pragma unroll
            for (int k = 0; k < 4; ++k) a2[k] = __fadd_rn(a2[k], w2[k]);
        }
    }
    v4f o;
#pragma unroll
    for (int k = 0; k < 4; ++k)
        o[k] = __fadd_rn(__fadd_rn(a0[k], a1[k]), __fadd_rn(a2[k], a3[k]));
    *(v4f*)(I1buf + ((size_t)tt * BATCH + b) * NN + j4) = o;   // cached store
}

// ---- phase 2a: lane-local scan. Block (b,q) = one wave, 256 neurons
// (n = q*256 + tid*4 + k). v1 exact (reset lane-local); v2 exact UNLESS a
// layer-1 spike occurs (I2=0 assumption); ids written as identity slots
// (exact when totals==0). Any spike -> flags[b]=1 -> fallback rewrites batch.
// Partial counts per (tt,b,q) packed in one u64: c1|cn1<<16|c2<<32|cn2<<48.
__global__ __launch_bounds__(64) void scan_kernel(
    const float* __restrict__ I1buf,
    const float* __restrict__ decay1, const float* __restrict__ decay2,
    const float* __restrict__ th1, const float* __restrict__ th2,
    const float* __restrict__ init1, const float* __restrict__ init2,
    const float* __restrict__ state_in, float* __restrict__ state_out,
    u64* __restrict__ pc, unsigned* __restrict__ flags,
    float* __restrict__ out, int t0, int nst)
{
    const int bid = blockIdx.x;
    const int b   = bid >> 2;
    const int q   = bid & 3;
    const int tid = threadIdx.x;            // 0..63 (one wave)
    const int n0  = (q << 8) + (tid << 2);  // neurons n0..n0+3

    float v1[4], v2[4], d1v[4], d2v[4], o1v[4], o2v[4];
    float t1v[4], t2v[4], t1bv[4], t2bv[4];
    const float* v1src = t0 ? (state_in + 0 * BATCH * NN) : init1;
    const float* v2src = t0 ? (state_in + 1 * BATCH * NN) : init2;
#pragma unroll
    for (int k = 0; k < 4; ++k) {
        const int n = n0 + k;
        v1[k] = v1src[b * NN + n];  v2[k] = v2src[b * NN + n];
        d1v[k] = decay1[n];  d2v[k] = decay2[n];
        t1v[k] = th1[n];     t2v[k] = th2[n];
        t1bv[k] = __fmul_rn(0.9f, t1v[k]);
        t2bv[k] = __fmul_rn(0.9f, t2v[k]);
        o1v[k] = __fadd_rn(1.0f, -d1v[k]);
        o2v[k] = __fadd_rn(1.0f, -d2v[k]);
    }

    float* out_ids1 = out;
    float* out_ids2 = out + (size_t)SEQ * BATCH * SS;
    float* out_st1  = out + (size_t)2 * SEQ * BATCH * SS + (size_t)2 * SEQ * BATCH * 2;
    float* out_st2  = out_st1 + (size_t)SEQ * BATCH * NN;

    const v4f idv = {(float)(n0 + 0), (float)(n0 + 1),
                     (float)(n0 + 2), (float)(n0 + 3)};
    const bool write_ids = (n0 + 3) < SS;          // q==0, tid<16
    u64 anyspike = 0;

    // depth-8 I1 prefetch ring (static indices; tail-clamped loads harmless)
    v4f f[8];
#pragma unroll
    for (int j = 0; j < 8; ++j) {
        const int tt = (j < nst) ? j : (nst - 1);
        f[j] = *(const v4f*)(I1buf + ((size_t)tt * BATCH + b) * NN + n0);
    }

    for (int g = 0; g < nst; g += 8) {
#pragma unroll
        for (int j = 0; j < 8; ++j) {
            const int tt = g + j;
            if (tt < nst) {                        // uniform guard
                const v4f cur = f[j];
                const int tp = (tt + 8 < nst) ? (tt + 8) : (nst - 1);
                f[j] = *(const v4f*)(I1buf + ((size_t)tp * BATCH + b) * NN + n0);

                u64 B1[4], Bn1[4], B2[4], Bn2[4];
#pragma unroll
                for (int k = 0; k < 4; ++k) {
                    v1[k] = __fadd_rn(__fmul_rn(d1v[k], v1[k]),
                                      __fmul_rn(o1v[k], cur[k]));
                    B1[k]  = __ballot(v1[k] > t1v[k]);
                    Bn1[k] = __ballot(v1[k] > t1bv[k]);
                    if ((B1[k] >> tid) & 1ull) v1[k] = 0.0f;     // exact reset
                    v2[k] = __fmul_rn(d2v[k], v2[k]);            // I2=0 spec
                    B2[k]  = __ballot(v2[k] > t2v[k]);
                    Bn2[k] = __ballot(v2[k] > t2bv[k]);
                    if ((B2[k] >> tid) & 1ull) v2[k] = 0.0f;     // exact reset
                }
                anyspike |= B1[0] | B1[1] | B1[2] | B1[3]
                          | B2[0] | B2[1] | B2[2] | B2[3];

                const u64 c1  = __popcll(B1[0]) + __popcll(B1[1])
                              + __popcll(B1[2]) + __popcll(B1[3]);
                const u64 cn1 = __popcll(Bn1[0]) + __popcll(Bn1[1])
                              + __popcll(Bn1[2]) + __popcll(Bn1[3]);
                const u64 c2  = __popcll(B2[0]) + __popcll(B2[1])
                              + __popcll(B2[2]) + __popcll(B2[3]);
                const u64 cn2 = __popcll(Bn2[0]) + __popcll(Bn2[1])
                              + __popcll(Bn2[2]) + __popcll(Bn2[3]);
                if (tid == 0)
                    pc[((size_t)tt * BATCH + b) * 4 + q] =
                        c1 | (cn1 << 16) | (c2 << 32) | (cn2 << 48);

                const size_t row = (size_t)(t0 + tt) * BATCH + b;
                const v4f s1 = {v1[0], v1[1], v1[2], v1[3]};
                const v4f s2 = {v2[0], v2[1], v2[2], v2[3]};
                __builtin_nontemporal_store(s1, (v4f*)(out_st1 + row * NN + n0));
                __builtin_nontemporal_store(s2, (v4f*)(out_st2 + row * NN + n0));
                if (write_ids) {                   // identity slots (totals==0)
                    __builtin_nontemporal_store(idv, (v4f*)(out_ids1 + row * SS + n0));
                    __builtin_nontemporal_store(idv, (v4f*)(out_ids2 + row * SS + n0));
                }
            }
        }
    }

    if (anyspike && tid == 0) flags[b] = 1u;       // batch needs exact fallback

#pragma unroll
    for (int k = 0; k < 4; ++k) {
        state_out[0 * BATCH * NN + b * NN + n0 + k] = v1[k];
        state_out[1 * BATCH * NN + b * NN + n0 + k] = v2[k];
    }
}

// ---- phase 2b: reduce per-quarter counts -> cnt outputs ----
__global__ __launch_bounds__(256) void reduce_kernel(
    const u64* __restrict__ pc, float* __restrict__ out, int t0, int nst)
{
    const int idx = blockIdx.x * 256 + threadIdx.x;
    if (idx >= nst * BATCH) return;
    const int tt = idx >> 6;
    const int b  = idx & 63;
    const u64 s = pc[(size_t)idx * 4 + 0] + pc[(size_t)idx * 4 + 1]
                + pc[(size_t)idx * 4 + 2] + pc[(size_t)idx * 4 + 3];
    float* out_cnt1 = out + (size_t)2 * SEQ * BATCH * SS;
    float* out_cnt2 = out_cnt1 + (size_t)SEQ * BATCH * 2;
    const size_t row = (size_t)(t0 + tt) * BATCH + b;
    out_cnt1[row * 2 + 0] = (float)(s & 0xFFFF);
    out_cnt1[row * 2 + 1] = (float)((s >> 16) & 0xFFFF);
    out_cnt2[row * 2 + 0] = (float)((s >> 32) & 0xFFFF);
    out_cnt2[row * 2 + 1] = (float)(s >> 48);
}

// ---- phase 2c: exact fallback (R13 lif body), only for flagged batches ----
__global__ __launch_bounds__(256, 1) void fallback_kernel(
    const float* __restrict__ I1buf, const float* __restrict__ W2,
    const float* __restrict__ decay1, const float* __restrict__ decay2,
    const float* __restrict__ th1, const float* __restrict__ th2,
    const float* __restrict__ init1, const float* __restrict__ init2,
    const float* __restrict__ state_in, float* __restrict__ state_out,
    const unsigned* __restrict__ flags, float* __restrict__ out,
    int t0, int nsteps)
{
    const int b = blockIdx.x;
    if (flags[b] == 0u) return;                    // common case: null work

    const int i    = threadIdx.x;
    const int lane = i & 63;
    const int w    = i >> 6;
    const int n0   = i << 2;

    __shared__ u64 lds_w[2][4];
    __shared__ u64 lds_wc[2][4];
    __shared__ int lds_slots[NN];

    float v1[4], v2[4], d1v[4], d2v[4], o1v[4], o2v[4];
    float t1v[4], t2v[4], t1bv[4], t2bv[4];
    const float* v1src = t0 ? (state_in + 0 * BATCH * NN) : init1;
    const float* v2src = t0 ? (state_in + 1 * BATCH * NN) : init2;
#pragma unroll
    for (int k = 0; k < 4; ++k) {
        const int n = n0 + k;
        v1[k] = v1src[b * NN + n];  v2[k] = v2src[b * NN + n];
        d1v[k] = decay1[n];  d2v[k] = decay2[n];
        t1v[k] = th1[n];     t2v[k] = th2[n];
        t1bv[k] = __fmul_rn(0.9f, t1v[k]);
        t2bv[k] = __fmul_rn(0.9f, t2v[k]);
        o1v[k] = __fadd_rn(1.0f, -d1v[k]);
        o2v[k] = __fadd_rn(1.0f, -d2v[k]);
    }

    float* out_ids1 = out;
    float* out_ids2 = out + (size_t)SEQ * BATCH * SS;
    float* out_cnt1 = out + (size_t)2 * SEQ * BATCH * SS;
    float* out_cnt2 = out_cnt1 + (size_t)SEQ * BATCH * 2;
    float* out_st1  = out_cnt2 + (size_t)SEQ * BATCH * 2;
    float* out_st2  = out_st1  + (size_t)SEQ * BATCH * NN;

    const u64 lmask_lt = (1ull << lane) - 1ull;

    u64 B1p[4], B2p[4];
    float v2pp[4];

    auto CONSUME = [&](int s, int ppar) {
        const u64* wp = lds_w[ppar];
        const u64 x0 = wp[0], x1 = wp[1], x2 = wp[2], x3 = wp[3];
        const u64 tot = x0 + x1 + x2 + x3;
        const u64 off = (w > 0 ? x0 : 0) + (w > 1 ? x1 : 0) + (w > 2 ? x2 : 0);
        const int totalA  = (int)(tot & 0xFFFF);
        const int total2A = (int)((tot >> 16) & 0xFFFF);
        const int woff1   = (int)(off & 0xFFFF);

        const int T1 = (int)(__popcll(B1p[0] & lmask_lt) + __popcll(B1p[1] & lmask_lt)
                           + __popcll(B1p[2] & lmask_lt) + __popcll(B1p[3] & lmask_lt));
        const size_t row = (size_t)s * BATCH + b;

        int run = 0;
        int lt1s[4]; bool bk1[4];
#pragma unroll
        for (int k = 0; k < 4; ++k) {
            bk1[k] = (B1p[k] >> lane) & 1ull;
            lt1s[k] = woff1 + T1 + run;
            run += bk1[k];
            const int slot = bk1[k] ? lt1s[k] : (totalA + (n0 + k) - lt1s[k]);
            if (slot < SS)
                __builtin_nontemporal_store((float)(n0 + k),
                                            &out_ids1[row * SS + slot]);
        }
        {
            const v4f sv = {v1[0], v1[1], v1[2], v1[3]};
            __builtin_nontemporal_store(sv, (v4f*)(out_st1 + row * NN + n0));
        }
        if (i == 0) {
            __builtin_nontemporal_store((float)totalA,  &out_cnt1[row * 2 + 0]);
            __builtin_nontemporal_store((float)total2A, &out_cnt1[row * 2 + 1]);
        }

        int totalB, total2B, woff2;
        u64 B2u[4]; float v2u[4];
        if (totalA > 0) {
#pragma unroll
            for (int k = 0; k < 4; ++k)
                if (bk1[k]) lds_slots[lt1s[k]] = n0 + k;
            RAW_BARRIER();
            float I2[4] = {0.0f, 0.0f, 0.0f, 0.0f};
            for (int kk = 0; kk < totalA; ++kk) {
                const int sid = lds_slots[kk];
#pragma unroll
                for (int k = 0; k < 4; ++k)
                    I2[k] = __fadd_rn(I2[k], W2[(size_t)(n0 + k) * NN + sid]);
            }
            u64 Bn2c[4];
#pragma unroll
            for (int k = 0; k < 4; ++k) {
                v2u[k] = __fadd_rn(v2pp[k], __fmul_rn(o2v[k], I2[k]));
                B2u[k] = __ballot(v2u[k] > t2v[k]);
                Bn2c[k] = __ballot(v2u[k] > t2bv[k]);
            }
            const u64 c2c  = __popcll(B2u[0]) + __popcll(B2u[1])
                           + __popcll(B2u[2]) + __popcll(B2u[3]);
            const u64 cn2c = __popcll(Bn2c[0]) + __popcll(Bn2c[1])
                           + __popcll(Bn2c[2]) + __popcll(Bn2c[3]);
            if (lane == 0) lds_wc[ppar][w] = c2c | (cn2c << 16);
            RAW_BARRIER();
            const u64* cp = lds_wc[ppar];
            const u64 ct = cp[0] + cp[1] + cp[2] + cp[3];
            const u64 co = (w > 0 ? cp[0] : 0) + (w > 1 ? cp[1] : 0)
                         + (w > 2 ? cp[2] : 0);
            totalB  = (int)(ct & 0xFFFF);
            total2B = (int)((ct >> 16) & 0xFFFF);
            woff2   = (int)(co & 0xFFFF);
        } else {
#pragma unroll
            for (int k = 0; k < 4; ++k) { B2u[k] = B2p[k]; v2u[k] = v2pp[k]; }
            totalB  = (int)((tot >> 32) & 0xFFFF);
            total2B = (int)(tot >> 48);
            woff2   = (int)((off >> 32) & 0xFFFF);
        }

        const int T2 = (int)(__popcll(B2u[0] & lmask_lt) + __popcll(B2u[1] & lmask_lt)
                           + __popcll(B2u[2] & lmask_lt) + __popcll(B2u[3] & lmask_lt));
        int run2 = 0;
        v4f sv2;
#pragma unroll
        for (int k = 0; k < 4; ++k) {
            const bool bk = (B2u[k] >> lane) & 1ull;
            const int lt = woff2 + T2 + run2;
            run2 += bk;
            const int slot = bk ? lt : (totalB + (n0 + k) - lt);
            if (slot < SS)
                __builtin_nontemporal_store((float)(n0 + k),
                                            &out_ids2[row * SS + slot]);
            sv2[k] = bk ? 0.0f : v2u[k];
            v2[k] = sv2[k];
        }
        __builtin_nontemporal_store(sv2, (v4f*)(out_st2 + row * NN + n0));
        if (i == 0) {
            __builtin_nontemporal_store((float)totalB,  &out_cnt2[row * 2 + 0]);
            __builtin_nontemporal_store((float)total2B, &out_cnt2[row * 2 + 1]);
        }
    };

    v4f f0 = *(const v4f*)(I1buf + ((size_t)0 * BATCH + b) * NN + n0);
    v4f f1 = (nsteps > 1)
        ? *(const v4f*)(I1buf + ((size_t)1 * BATCH + b) * NN + n0) : f0;

    for (int tt = 0; tt < nsteps; ++tt) {
        const int par = tt & 1;
        v4f f2 = f0;
        if (tt + 2 < nsteps)
            f2 = *(const v4f*)(I1buf + ((size_t)(tt + 2) * BATCH + b) * NN + n0);

        if (tt > 0) CONSUME(t0 + tt - 1, par ^ 1);

        const v4f f = f0; f0 = f1; f1 = f2;
        u64 Bn1[4], Bn2[4];
#pragma unroll
        for (int k = 0; k < 4; ++k) {
            v1[k] = __fadd_rn(__fmul_rn(d1v[k], v1[k]), __fmul_rn(o1v[k], f[k]));
            B1p[k] = __ballot(v1[k] > t1v[k]);
            Bn1[k] = __ballot(v1[k] > t1bv[k]);
            if ((B1p[k] >> lane) & 1ull) v1[k] = 0.0f;
            v2pp[k] = __fmul_rn(d2v[k], v2[k]);
            B2p[k] = __ballot(v2pp[k] > t2v[k]);
            Bn2[k] = __ballot(v2pp[k] > t2bv[k]);
        }
        const u64 c1  = __popcll(B1p[0]) + __popcll(B1p[1])
                      + __popcll(B1p[2]) + __popcll(B1p[3]);
        const u64 cn1 = __popcll(Bn1[0]) + __popcll(Bn1[1])
                      + __popcll(Bn1[2]) + __popcll(Bn1[3]);
        const u64 c2  = __popcll(B2p[0]) + __popcll(B2p[1])
                      + __popcll(B2p[2]) + __popcll(B2p[3]);
        const u64 cn2 = __popcll(Bn2[0]) + __popcll(Bn2[1])
                      + __popcll(Bn2[2]) + __popcll(Bn2[3]);
        if (lane == 0)
            lds_w[par][w] = c1 | (cn1 << 16) | (c2 << 32) | (cn2 << 48);

        RAW_BARRIER();
    }

    CONSUME(t0 + nsteps - 1, (nsteps - 1) & 1);

#pragma unroll
    for (int k = 0; k < 4; ++k) {
        state_out[0 * BATCH * NN + b * NN + n0 + k] = v1[k];
        state_out[1 * BATCH * NN + b * NN + n0 + k] = v2[k];
    }
}

extern "C" void kernel_launch(void* const* d_in, const int* in_sizes, int n_in,
                              void* d_out, int out_size, void* d_ws, size_t ws_size,
                              hipStream_t stream) {
    const float* W1     = (const float*)d_in[0];
    const float* W2     = (const float*)d_in[1];
    const float* decay1 = (const float*)d_in[2];
    const float* decay2 = (const float*)d_in[3];
    const float* th1    = (const float*)d_in[4];
    const float* th2    = (const float*)d_in[5];
    const float* init1  = (const float*)d_in[6];
    const float* init2  = (const float*)d_in[7];
    const int* inp_ids  = (const int*)d_in[8];
    const int* inp_num  = (const int*)d_in[9];
    float* out = (float*)d_out;

    char* p = (char*)d_ws;
    float* W1T    = (float*)p;                         p += (size_t)NN * NN * 4;
    float* stateA = (float*)p;                         p += (size_t)2 * BATCH * NN * 4;
    float* stateB = (float*)p;                         p += (size_t)2 * BATCH * NN * 4;
    u64*   pc     = (u64*)p;                           p += (size_t)SEQ * BATCH * 4 * 8;
    unsigned* flags = (unsigned*)p;                    p += 256;
    float* I1buf  = (float*)p;
    const size_t used  = (size_t)(p - (char*)d_ws);
    const size_t avail = ws_size > used ? ws_size - used : 0;
    int tc = (int)(avail / ((size_t)BATCH * NN * 4));
    if (tc > SEQ) tc = SEQ;
    if (tc < 1) tc = 1;

    dim3 tb(32, 8, 1), tg(NN / 32, NN / 32, 1);
    transpose1<<<tg, tb, 0, stream>>>(W1, W1T);

    float* sin  = stateA;
    float* sout = stateB;
    for (int t0 = 0; t0 < SEQ; t0 += tc) {
        const int nst = (SEQ - t0 < tc) ? (SEQ - t0) : tc;
        hipMemsetAsync(flags, 0, BATCH * sizeof(unsigned), stream);
        gather_kernel<<<nst * BATCH, 256, 0, stream>>>(W1T, inp_ids, inp_num,
                                                       I1buf, t0);
        scan_kernel<<<4 * BATCH, 64, 0, stream>>>(I1buf, decay1, decay2, th1, th2,
                                                  init1, init2, sin, sout,
                                                  pc, flags, out, t0, nst);
        reduce_kernel<<<(nst * BATCH + 255) / 256, 256, 0, stream>>>(pc, out, t0, nst);
        fallback_kernel<<<BATCH, 256, 0, stream>>>(I1buf, W2, decay1, decay2,
                                                   th1, th2, init1, init2,
                                                   sin, sout, flags, out, t0, nst);
        float* tmp = sin; sin = sout; sout = tmp;
    }
}